// Round 9
// baseline (3704.297 us; speedup 1.0000x reference)
//
#include <hip/hip_runtime.h>

#define HD 256
#define ID 32
#define OD 10
#define SEQ 512
#define SMEM_BYTES 159744   // 16K h double-buffer + 4K bias + 136K weight frags

typedef __attribute__((ext_vector_type(4))) float f32x4;
typedef __attribute__((ext_vector_type(8))) unsigned short u16x8;
typedef __attribute__((ext_vector_type(8))) __bf16 bf16x8;

static __device__ __forceinline__ unsigned short f2bf(float f) {
  unsigned u = __builtin_bit_cast(unsigned, f);
  u += 0x7fffu + ((u >> 16) & 1u);          // RNE
  return (unsigned short)(u >> 16);
}
static __device__ __forceinline__ float bf2f(unsigned short s) {
  unsigned u = ((unsigned)s) << 16;
  return __builtin_bit_cast(float, u);
}
static __device__ __forceinline__ f32x4 mfma16(u16x8 a, u16x8 b, f32x4 c) {
  return __builtin_amdgcn_mfma_f32_16x16x32_bf16(
      __builtin_bit_cast(bf16x8, a), __builtin_bit_cast(bf16x8, b), c, 0, 0, 0);
}
static __device__ __forceinline__ float fast_sigmoid(float x) {
  return 1.f / (1.f + __expf(-x));
}
static __device__ __forceinline__ float fast_tanh(float x) {
  return 1.f - 2.f / (__expf(2.f * x) + 1.f);
}

// ---- per-wave fragment class map: c=unit-subtile 0..3, g=gate, kt=k-tile ----
// class 0 = register-resident (94), 1 = LDS-resident (34), 2 = L2-streamed (16)
constexpr int cls(int c, int g, int kt) {
  if (kt == 0) return 2;                       // Wx frags: streamed per phase
  if (kt >= 7) return 1;                       // kt 7,8 all (c,g): 32 frags
  if (kt == 6 && c == 3 && g >= 2) return 1;   // +2 to fit LDS budget
  return 0;
}
constexpr int cidx(int c, int g, int kt) {     // index within its class
  int n = 0;
  for (int cc = 0; cc < 4; ++cc)
    for (int gg = 0; gg < 4; ++gg)
      for (int k2 = 0; k2 < 9; ++k2) {
        if (cc == c && gg == g && k2 == kt) return n;
        if (cls(cc, gg, k2) == cls(c, g, kt)) ++n;
      }
  return -1;
}

// ---------------------------------------------------------------------------
// Pack [Wx;Wh] (K=288 x N=1024 bf16) fragment-major for 4-wave geometry.
// frag f = w*144 + (c*4+g)*9 + kt  (w=wave 0..3 owns units [64w,64w+64))
// lane l slot i -> W[k = 32kt + 8*(l>>4)+i][unit U = 64w + 16c + (l&15)] gate g
// ---------------------------------------------------------------------------
__global__ void pack_w(const float* __restrict__ Wgx, const float* __restrict__ Wgh,
                       const float* __restrict__ Wix, const float* __restrict__ Wih,
                       const float* __restrict__ Wfx, const float* __restrict__ Wfh,
                       const float* __restrict__ Wox, const float* __restrict__ Woh,
                       unsigned short* __restrict__ Wpk) {
  int p = blockIdx.x * blockDim.x + threadIdx.x;
  if (p >= 576 * 64) return;
  int f = p >> 6, l = p & 63;
  int w = f / 144, r = f % 144;
  int cg = r / 9, kt = r % 9;
  int c = cg >> 2, g = cg & 3;
  int U = w * 64 + c * 16 + (l & 15);
  const float* Wx[4] = {Wgx, Wix, Wfx, Wox};
  const float* Wh[4] = {Wgh, Wih, Wfh, Woh};
  u16x8 v;
  #pragma unroll
  for (int i = 0; i < 8; ++i) {
    int k = kt * 32 + 8 * (l >> 4) + i;
    float val = (k < ID) ? Wx[g][k * HD + U] : Wh[g][(k - ID) * HD + U];
    v[i] = f2bf(val);
  }
  *(u16x8*)(Wpk + ((size_t)f << 9) + (l << 3)) = v;
}

// ---------------------------------------------------------------------------
// 16 fully-independent WGs (one per 16-row batch group), 256 threads
// (4 waves, 1/SIMD -> 512-reg unified file per wave). All weights on-CU:
// 94 frags regs + 34 frags LDS per wave; 16 Wx frags streamed from L2/step.
// h state in LDS double-buffer, XOR-chunk swizzle (conflict-free b128).
// No inter-WG communication of any kind.
// ---------------------------------------------------------------------------
__global__ void __launch_bounds__(256, 1) lstm_rec(
    const float* __restrict__ x, const unsigned short* __restrict__ Wpk,
    const float* __restrict__ bgp, const float* __restrict__ bip,
    const float* __restrict__ bfp, const float* __restrict__ bop,
    const float* __restrict__ Wph, const float* __restrict__ bpp,
    float* __restrict__ out) {
  extern __shared__ __align__(16) char smem[];
  unsigned short* hbuf = (unsigned short*)smem;            // [2][16][256] bf16
  float* blds = (float*)(smem + 16384);                    // [4][256] bias
  unsigned short* wlds = (unsigned short*)(smem + 20480);  // [4][34][512]

  const int tid = threadIdx.x;
  const int w = tid >> 6, l = tid & 63;
  const int l15 = l & 15, l4 = l >> 4;
  const int b0 = blockIdx.x * 16;

  const unsigned short* wbase = Wpk + (((size_t)w * 144) << 9) + (l << 3);
  unsigned short* wlw = wlds + w * (34 * 512) + (l << 3);

  // ---- stage LDS-resident weight frags ----
  #pragma unroll
  for (int c = 0; c < 4; ++c)
    #pragma unroll
    for (int g = 0; g < 4; ++g)
      #pragma unroll
      for (int kt = 1; kt <= 8; ++kt)
        if (cls(c, g, kt) == 1) {
          u16x8 v = *(const u16x8*)(wbase +
                     ((size_t)((c * 4 + g) * 9 + kt) << 9));
          *(u16x8*)(wlw + (cidx(c, g, kt) << 9)) = v;
        }
  // ---- bias to LDS; zero h parity 0 ----
  blds[tid] = bgp[tid];
  blds[256 + tid] = bip[tid];
  blds[512 + tid] = bfp[tid];
  blds[768 + tid] = bop[tid];
  for (int idx = tid; idx < 4096; idx += 256) hbuf[idx] = 0;

  // ---- register-resident weight frags (VGPR+AGPR unified file) ----
  u16x8 wreg[94];
  #pragma unroll
  for (int c = 0; c < 4; ++c)
    #pragma unroll
    for (int g = 0; g < 4; ++g)
      #pragma unroll
      for (int kt = 1; kt <= 8; ++kt)
        if (cls(c, g, kt) == 0)
          wreg[cidx(c, g, kt)] = *(const u16x8*)(wbase +
              ((size_t)((c * 4 + g) * 9 + kt) << 9));

  float cst[16];
  #pragma unroll
  for (int i = 0; i < 16; ++i) cst[i] = 0.f;

  __syncthreads();

  #pragma unroll 1
  for (int t = 0; t < SEQ; ++t) {
    // ---- A fragments: ax from x_t; ah[8] = h_{t-1} (swizzled LDS) ----
    const float* xp = x + (((size_t)(b0 + l15)) * SEQ + t) * ID + 8 * l4;
    float4 v0 = *(const float4*)xp;
    float4 v1 = *(const float4*)(xp + 4);
    u16x8 ax;
    ax[0] = f2bf(v0.x); ax[1] = f2bf(v0.y); ax[2] = f2bf(v0.z); ax[3] = f2bf(v0.w);
    ax[4] = f2bf(v1.x); ax[5] = f2bf(v1.y); ax[6] = f2bf(v1.z); ax[7] = f2bf(v1.w);
    const unsigned short* hb = hbuf + (t & 1) * 4096 + l15 * 256;
    u16x8 ah[8];
    #pragma unroll
    for (int kt = 1; kt <= 8; ++kt) {
      int c32 = 4 * (kt - 1) + l4;
      ah[kt - 1] = *(const u16x8*)(hb + ((c32 ^ l15) << 3));
    }
    unsigned short* ho = hbuf + ((t & 1) ^ 1) * 4096;

    // ---- 4 phases of 16 units each ----
    #pragma unroll
    for (int c = 0; c < 4; ++c) {
      // stream this phase's Wx frags now; consumed after the 32-MFMA chain
      u16x8 sf0 = *(const u16x8*)(wbase + ((size_t)((c * 4 + 0) * 9) << 9));
      u16x8 sf1 = *(const u16x8*)(wbase + ((size_t)((c * 4 + 1) * 9) << 9));
      u16x8 sf2 = *(const u16x8*)(wbase + ((size_t)((c * 4 + 2) * 9) << 9));
      u16x8 sf3 = *(const u16x8*)(wbase + ((size_t)((c * 4 + 3) * 9) << 9));
      const int ub = 64 * w + 16 * c + l15;
      f32x4 acc[4];
      #pragma unroll
      for (int g = 0; g < 4; ++g) {
        float b = blds[g * 256 + ub];
        acc[g] = f32x4{b, b, b, b};
      }
      #pragma unroll
      for (int kt = 1; kt <= 8; ++kt)
        #pragma unroll
        for (int g = 0; g < 4; ++g) {
          u16x8 bw;
          if (cls(c, g, kt) == 0) bw = wreg[cidx(c, g, kt)];
          else bw = *(const u16x8*)(wlw + (cidx(c, g, kt) << 9));
          acc[g] = mfma16(ah[kt - 1], bw, acc[g]);
        }
      acc[0] = mfma16(ax, sf0, acc[0]);
      acc[1] = mfma16(ax, sf1, acc[1]);
      acc[2] = mfma16(ax, sf2, acc[2]);
      acc[3] = mfma16(ax, sf3, acc[3]);
      // ---- gates; D layout: col(unit)=l15, row(batch)=4*l4+i ----
      #pragma unroll
      for (int i = 0; i < 4; ++i) {
        float gg = fast_tanh(acc[0][i]);
        float ii = fast_sigmoid(acc[1][i]);
        float ff = fast_sigmoid(acc[2][i]);
        float oo = fast_sigmoid(acc[3][i]);
        float cc = gg * ii + cst[c * 4 + i] * ff;
        cst[c * 4 + i] = cc;
        float hh = fast_tanh(cc) * oo;
        int r2 = 4 * l4 + i;
        int cu = ub >> 3;
        ho[r2 * 256 + ((cu ^ r2) << 3) + (ub & 7)] = f2bf(hh);
      }
    }
    __syncthreads();   // h_t parity buffer complete for next step
  }

  // ---- epilogue: final h is in parity 0; logits + softmax, own 16 rows ----
  float* lbuf = (float*)(smem + 16384);   // bias region dead now
  __syncthreads();
  if (tid < 16 * OD) {
    int eb = tid & 15, ej = tid >> 4;
    float s = bpp[ej];
    for (int k = 0; k < HD; ++k) {
      int ck = (k >> 3) ^ eb;
      s += bf2f(hbuf[eb * 256 + (ck << 3) + (k & 7)]) * Wph[k * OD + ej];
    }
    lbuf[eb * OD + ej] = s;
  }
  __syncthreads();
  if (tid < 16) {
    float m = -1e30f;
    #pragma unroll
    for (int j = 0; j < OD; ++j) m = fmaxf(m, lbuf[tid * OD + j]);
    float e[OD], sum = 0.f;
    #pragma unroll
    for (int j = 0; j < OD; ++j) { e[j] = __expf(lbuf[tid * OD + j] - m); sum += e[j]; }
    float inv = 1.f / sum;
    #pragma unroll
    for (int j = 0; j < OD; ++j) out[(b0 + tid) * OD + j] = e[j] * inv;
  }
}

extern "C" void kernel_launch(void* const* d_in, const int* in_sizes, int n_in,
                              void* d_out, int out_size, void* d_ws, size_t ws_size,
                              hipStream_t stream) {
  const float* X   = (const float*)d_in[0];
  const float* Wgx = (const float*)d_in[1];
  const float* Wgh = (const float*)d_in[2];
  const float* bg  = (const float*)d_in[3];
  const float* Wix = (const float*)d_in[4];
  const float* Wih = (const float*)d_in[5];
  const float* bi  = (const float*)d_in[6];
  const float* Wfx = (const float*)d_in[7];
  const float* Wfh = (const float*)d_in[8];
  const float* bf  = (const float*)d_in[9];
  const float* Wox = (const float*)d_in[10];
  const float* Woh = (const float*)d_in[11];
  const float* bo  = (const float*)d_in[12];
  const float* Wph = (const float*)d_in[13];
  const float* bp  = (const float*)d_in[14];

  unsigned short* Wpk = (unsigned short*)d_ws;   // 576 KB packed weights only

  (void)hipFuncSetAttribute((const void*)lstm_rec,
                            hipFuncAttributeMaxDynamicSharedMemorySize,
                            SMEM_BYTES);

  pack_w<<<dim3(72), dim3(512), 0, stream>>>(Wgx, Wgh, Wix, Wih, Wfx, Wfh,
                                             Wox, Woh, Wpk);
  lstm_rec<<<dim3(16), dim3(256), SMEM_BYTES, stream>>>(
      X, Wpk, bg, bi, bf, bo, Wph, bp, (float*)d_out);
}